// Round 13
// baseline (566.338 us; speedup 1.0000x reference)
//
#include <hip/hip_runtime.h>
#include <math.h>

// Problem constants (B=2, T=2048, C=1024, H=16, D=64)
#define Bn 2
#define Tn 2048
#define Cn 1024
#define Hn 16
#define Dn 64

typedef short  bf16x8 __attribute__((ext_vector_type(8)));  // 8 bf16 (4 VGPRs)
typedef short  s16x4  __attribute__((ext_vector_type(4)));  // 8-byte LDS store
typedef float  f32x4  __attribute__((ext_vector_type(4)));  // MFMA accumulator

// fp32 -> bf16 round-to-nearest-even
static __device__ __forceinline__ unsigned short f32_bf16(float f) {
    unsigned u = __float_as_uint(f);
    return (unsigned short)((u + 0x7fffu + ((u >> 16) & 1u)) >> 16);
}
static __device__ __forceinline__ float bf16_f32(unsigned short h) {
    return __uint_as_float(((unsigned)h) << 16);
}
// split fp32x4 into hi/lo bf16x4 pair and store (8B each)
static __device__ __forceinline__ void split_store(short* dh, short* dl, float4 v) {
    unsigned short h0 = f32_bf16(v.x), h1 = f32_bf16(v.y),
                   h2 = f32_bf16(v.z), h3 = f32_bf16(v.w);
    *(s16x4*)dh = (s16x4){(short)h0, (short)h1, (short)h2, (short)h3};
    *(s16x4*)dl = (s16x4){(short)f32_bf16(v.x - bf16_f32(h0)),
                          (short)f32_bf16(v.y - bf16_f32(h1)),
                          (short)f32_bf16(v.z - bf16_f32(h2)),
                          (short)f32_bf16(v.w - bf16_f32(h3))};
}

// ---------------------------------------------------------------------------
// QKV GEMM (M=4096, N=3072, K=1024), MFMA bf16x3 — round-8-verified core.
// Epilogue: col region 0 (Q) -> fp32 qbuf [4096][1024];
// region 1 (K) -> hi/lo bf16 [b,h][t][64] (natural);
// region 2 (V) -> hi/lo bf16 [b,h][d][2048] (TRANSPOSED; 4 consecutive
// t per lane -> s16x4 stores). Converts K/V exactly once (attn re-used them
// ~16.5x each when converting per-tile).
// ---------------------------------------------------------------------------
__global__ __launch_bounds__(256) void gemm_qkv(const float* __restrict__ A,
                                                const float* __restrict__ B,
                                                const float* __restrict__ bias,
                                                float* __restrict__ qbuf,
                                                short* __restrict__ kh_,
                                                short* __restrict__ kl_,
                                                short* __restrict__ vth_,
                                                short* __restrict__ vtl_) {
    const int M = 4096, N = 3072, K = 1024;
    __shared__ short Ah[128][40];
    __shared__ short Al[128][40];
    __shared__ short Bh[128][40];   // transposed: Bh[n][k]
    __shared__ short Bl[128][40];

    const int tid = threadIdx.x;
    const int m0 = blockIdx.y * 128;
    const int n0 = blockIdx.x * 128;
    const int w  = tid >> 6;
    const int l  = tid & 63;
    const int wr = w >> 1;
    const int wc = w & 1;
    const int lr = l & 15;
    const int g8 = (l >> 4) * 8;

    const int a_in  = tid & 7;
    const int a_r0  = tid >> 3;
    const int q     = tid >> 2;
    const int e     = tid & 3;
    const int b_n   = 4 * (q & 31);
    const int b_kb  = 16 * (q >> 5);

    f32x4 acc[4][4];
    #pragma unroll
    for (int i = 0; i < 4; ++i)
        #pragma unroll
        for (int j = 0; j < 4; ++j)
            acc[i][j] = (f32x4){0.f, 0.f, 0.f, 0.f};

    for (int k0 = 0; k0 < K; k0 += 32) {
        #pragma unroll
        for (int c4 = 0; c4 < 4; ++c4) {
            const int row = a_r0 + 32 * c4;
            const float4 v = *(const float4*)(A + (size_t)(m0 + row) * K + k0 + 4 * a_in);
            split_store(&Ah[row][4 * a_in], &Al[row][4 * a_in], v);
        }
        #pragma unroll
        for (int c = 0; c < 4; ++c) {
            const int krow = b_kb + 4 * c + e;
            const float4 v = *(const float4*)(B + (size_t)(k0 + krow) * N + n0 + b_n);
            float4 b1, u, b2, t;
            b1.x = __shfl_xor(v.x, 1); b1.y = __shfl_xor(v.y, 1);
            b1.z = __shfl_xor(v.z, 1); b1.w = __shfl_xor(v.w, 1);
            if (e & 1) { u.x = b1.y; u.y = v.y; u.z = b1.w; u.w = v.w; }
            else       { u.x = v.x;  u.y = b1.x; u.z = v.z; u.w = b1.z; }
            b2.x = __shfl_xor(u.x, 2); b2.y = __shfl_xor(u.y, 2);
            b2.z = __shfl_xor(u.z, 2); b2.w = __shfl_xor(u.w, 2);
            if (e & 2) { t.x = b2.z; t.y = b2.w; t.z = u.z; t.w = u.w; }
            else       { t.x = u.x;  t.y = u.y;  t.z = b2.x; t.w = b2.y; }
            const int nrow = b_n + e;
            const int kcol = b_kb + 4 * c;
            split_store(&Bh[nrow][kcol], &Bl[nrow][kcol], t);
        }
        __syncthreads();

        bf16x8 fah[4], fal[4], fbh[4], fbl[4];
        #pragma unroll
        for (int i = 0; i < 4; ++i) {
            fah[i] = *(const bf16x8*)&Ah[64 * wr + 16 * i + lr][g8];
            fal[i] = *(const bf16x8*)&Al[64 * wr + 16 * i + lr][g8];
            fbh[i] = *(const bf16x8*)&Bh[64 * wc + 16 * i + lr][g8];
            fbl[i] = *(const bf16x8*)&Bl[64 * wc + 16 * i + lr][g8];
        }
        #pragma unroll
        for (int i = 0; i < 4; ++i)
            #pragma unroll
            for (int j = 0; j < 4; ++j) {
                acc[i][j] = __builtin_amdgcn_mfma_f32_16x16x32_bf16(fah[i], fbh[j], acc[i][j], 0, 0, 0);
                acc[i][j] = __builtin_amdgcn_mfma_f32_16x16x32_bf16(fah[i], fbl[j], acc[i][j], 0, 0, 0);
                acc[i][j] = __builtin_amdgcn_mfma_f32_16x16x32_bf16(fal[i], fbh[j], acc[i][j], 0, 0, 0);
            }
        __syncthreads();
    }

    // ---- region-dependent epilogue (n0 is 128-aligned; regions 1024-aligned)
    const int region = n0 >> 10;
    if (region == 0) {
        // Q -> fp32 qbuf [4096][1024]
        #pragma unroll
        for (int j = 0; j < 4; ++j) {
            const int col = n0 + 64 * wc + 16 * j + lr;        // < 1024
            const float bv = bias[col];
            #pragma unroll
            for (int i = 0; i < 4; ++i) {
                const int rbase = m0 + 64 * wr + 16 * i + (l >> 4) * 4;
                #pragma unroll
                for (int r = 0; r < 4; ++r)
                    qbuf[(size_t)(rbase + r) * 1024 + col] = acc[i][j][r] + bv;
            }
        }
    } else if (region == 1) {
        // K -> hi/lo bf16, natural [b,h][t][64]
        #pragma unroll
        for (int j = 0; j < 4; ++j) {
            const int colg = n0 + 64 * wc + 16 * j + lr;
            const int colp = colg - 1024;
            const int h = colp >> 6, d = colp & 63;
            const float bv = bias[colg];
            #pragma unroll
            for (int i = 0; i < 4; ++i) {
                const int rbase = m0 + 64 * wr + 16 * i + (l >> 4) * 4;
                const int b  = rbase >> 11;
                const int t0 = rbase & 2047;
                const size_t base = ((size_t)(b * Hn + h) * Tn + t0) * 64 + d;
                #pragma unroll
                for (int r = 0; r < 4; ++r) {
                    const float v = acc[i][j][r] + bv;
                    const unsigned short hh = f32_bf16(v);
                    kh_[base + (size_t)r * 64] = (short)hh;
                    kl_[base + (size_t)r * 64] = (short)f32_bf16(v - bf16_f32(hh));
                }
            }
        }
    } else {
        // V -> hi/lo bf16, TRANSPOSED [b,h][d][2048]; 4 consecutive t -> s16x4
        #pragma unroll
        for (int j = 0; j < 4; ++j) {
            const int colg = n0 + 64 * wc + 16 * j + lr;
            const int colp = colg - 2048;
            const int h = colp >> 6, d = colp & 63;
            const float bv = bias[colg];
            #pragma unroll
            for (int i = 0; i < 4; ++i) {
                const int rbase = m0 + 64 * wr + 16 * i + (l >> 4) * 4;
                const int b  = rbase >> 11;
                const int t0 = rbase & 2047;
                float4 v4 = {acc[i][j][0] + bv, acc[i][j][1] + bv,
                             acc[i][j][2] + bv, acc[i][j][3] + bv};
                const size_t base = ((size_t)(b * Hn + h) * 64 + d) * Tn + t0;
                split_store(vth_ + base, vtl_ + base, v4);
            }
        }
    }
}

// ---------------------------------------------------------------------------
// MFMA GEMM, bf16 hi/lo x3 — HW-VERIFIED round 8. Used for the projection.
// ---------------------------------------------------------------------------
__global__ __launch_bounds__(256) void gemm_mfma3(const float* __restrict__ A,
                                                  const float* __restrict__ B,
                                                  const float* __restrict__ bias,
                                                  float* __restrict__ C,
                                                  int M, int N, int K) {
    __shared__ short Ah[128][40];
    __shared__ short Al[128][40];
    __shared__ short Bh[128][40];
    __shared__ short Bl[128][40];

    const int tid = threadIdx.x;
    const int m0 = blockIdx.y * 128;
    const int n0 = blockIdx.x * 128;
    const int w  = tid >> 6;
    const int l  = tid & 63;
    const int wr = w >> 1;
    const int wc = w & 1;
    const int lr = l & 15;
    const int g8 = (l >> 4) * 8;

    const int a_in  = tid & 7;
    const int a_r0  = tid >> 3;
    const int q     = tid >> 2;
    const int e     = tid & 3;
    const int b_n   = 4 * (q & 31);
    const int b_kb  = 16 * (q >> 5);

    f32x4 acc[4][4];
    #pragma unroll
    for (int i = 0; i < 4; ++i)
        #pragma unroll
        for (int j = 0; j < 4; ++j)
            acc[i][j] = (f32x4){0.f, 0.f, 0.f, 0.f};

    for (int k0 = 0; k0 < K; k0 += 32) {
        #pragma unroll
        for (int c4 = 0; c4 < 4; ++c4) {
            const int row = a_r0 + 32 * c4;
            const float4 v = *(const float4*)(A + (size_t)(m0 + row) * K + k0 + 4 * a_in);
            split_store(&Ah[row][4 * a_in], &Al[row][4 * a_in], v);
        }
        #pragma unroll
        for (int c = 0; c < 4; ++c) {
            const int krow = b_kb + 4 * c + e;
            const float4 v = *(const float4*)(B + (size_t)(k0 + krow) * N + n0 + b_n);
            float4 b1, u, b2, t;
            b1.x = __shfl_xor(v.x, 1); b1.y = __shfl_xor(v.y, 1);
            b1.z = __shfl_xor(v.z, 1); b1.w = __shfl_xor(v.w, 1);
            if (e & 1) { u.x = b1.y; u.y = v.y; u.z = b1.w; u.w = v.w; }
            else       { u.x = v.x;  u.y = b1.x; u.z = v.z; u.w = b1.z; }
            b2.x = __shfl_xor(u.x, 2); b2.y = __shfl_xor(u.y, 2);
            b2.z = __shfl_xor(u.z, 2); b2.w = __shfl_xor(u.w, 2);
            if (e & 2) { t.x = b2.z; t.y = b2.w; t.z = u.z; t.w = u.w; }
            else       { t.x = u.x;  t.y = u.y;  t.z = b2.x; t.w = b2.y; }
            const int nrow = b_n + e;
            const int kcol = b_kb + 4 * c;
            split_store(&Bh[nrow][kcol], &Bl[nrow][kcol], t);
        }
        __syncthreads();

        bf16x8 fah[4], fal[4], fbh[4], fbl[4];
        #pragma unroll
        for (int i = 0; i < 4; ++i) {
            fah[i] = *(const bf16x8*)&Ah[64 * wr + 16 * i + lr][g8];
            fal[i] = *(const bf16x8*)&Al[64 * wr + 16 * i + lr][g8];
            fbh[i] = *(const bf16x8*)&Bh[64 * wc + 16 * i + lr][g8];
            fbl[i] = *(const bf16x8*)&Bl[64 * wc + 16 * i + lr][g8];
        }
        #pragma unroll
        for (int i = 0; i < 4; ++i)
            #pragma unroll
            for (int j = 0; j < 4; ++j) {
                acc[i][j] = __builtin_amdgcn_mfma_f32_16x16x32_bf16(fah[i], fbh[j], acc[i][j], 0, 0, 0);
                acc[i][j] = __builtin_amdgcn_mfma_f32_16x16x32_bf16(fah[i], fbl[j], acc[i][j], 0, 0, 0);
                acc[i][j] = __builtin_amdgcn_mfma_f32_16x16x32_bf16(fal[i], fbh[j], acc[i][j], 0, 0, 0);
            }
        __syncthreads();
    }

    #pragma unroll
    for (int j = 0; j < 4; ++j) {
        const int col = n0 + 64 * wc + 16 * j + lr;
        const float bv = bias[col];
        #pragma unroll
        for (int i = 0; i < 4; ++i) {
            const int rbase = m0 + 64 * wr + 16 * i + (l >> 4) * 4;
            #pragma unroll
            for (int r = 0; r < 4; ++r)
                C[(size_t)(rbase + r) * N + col] = acc[i][j][r] + bv;
        }
    }
}

// ---------------------------------------------------------------------------
// MFMA flash attention v2 (causal): K/V pre-converted bf16 hi/lo in global
// (K natural [b,h][t][d], V transposed [b,h][d][t]) -> B-frags loaded DIRECT
// from global (L2-resident: 512 KB/head, head pinned per-XCD by bid map).
// No staging, no transpose, no main-loop barriers. Block = 128 q-rows of one
// (b,h); 4 waves x 32 q-rows; each wave loops to its own diagonal tile.
// P round-trip through wave-private LDS (wave-synchronous, round-10-verified).
// Fragment conventions = round-8/10 verified:
//   A/B-frag: row/col = lane&15, k-slot = 32*chunk + (lane>>4)*8 + i
//   C/D:      col = lane&15, row = (lane>>4)*4 + reg
// ---------------------------------------------------------------------------
__global__ __launch_bounds__(256) void attn_mfma2(const float* __restrict__ qbuf,
                                                  const short* __restrict__ kh_,
                                                  const short* __restrict__ kl_,
                                                  const short* __restrict__ vth_,
                                                  const short* __restrict__ vtl_,
                                                  float* __restrict__ y) {
    __shared__ short Ph[128][72], Pl[128][72];   // Q staging, then per-wave P

    const int tid = threadIdx.x;
    const int w   = tid >> 6;        // wave 0..3 -> q rows [32w, 32w+32)
    const int ln  = tid & 63;
    const int g   = ln >> 4;         // 0..3
    const int c16 = ln & 15;

    // bid -> (b,h,qb): consecutive bids = different heads (head -> fixed XCD
    // under round-robin dispatch); largest q-block first.
    const int bid = blockIdx.x;      // 0..511
    const int p   = bid & 31;
    const int qb  = 15 - (bid >> 5); // 15..0
    const int b   = p >> 4;
    const int h   = p & 15;

    // ---- stage Q tile (128 x 64 fp32) -> hi/lo LDS, hoist frags ----
    {
        const int row = tid >> 1;
        const int ch  = (tid & 1) * 32;
        const float* qp = qbuf + (size_t)(b * Tn + 128 * qb + row) * Cn + h * Dn + ch;
        #pragma unroll
        for (int cc = 0; cc < 8; ++cc) {
            const float4 v = *(const float4*)(qp + 4 * cc);
            split_store(&Ph[row][ch + 4 * cc], &Pl[row][ch + 4 * cc], v);
        }
    }
    __syncthreads();
    bf16x8 qh[2][2], ql[2][2];
    #pragma unroll
    for (int a = 0; a < 2; ++a) {
        const int row = 32 * w + 16 * a + c16;
        qh[a][0] = *(const bf16x8*)&Ph[row][8 * g];
        qh[a][1] = *(const bf16x8*)&Ph[row][32 + 8 * g];
        ql[a][0] = *(const bf16x8*)&Pl[row][8 * g];
        ql[a][1] = *(const bf16x8*)&Pl[row][32 + 8 * g];
    }
    __syncthreads();   // Q LDS dead; regions become wave-private P space

    f32x4 Y[2][4];
    float m[2][4], lsum[2][4];
    #pragma unroll
    for (int a = 0; a < 2; ++a)
        #pragma unroll
        for (int j = 0; j < 4; ++j) Y[a][j] = (f32x4){0.f, 0.f, 0.f, 0.f};
    #pragma unroll
    for (int a = 0; a < 2; ++a)
        #pragma unroll
        for (int r = 0; r < 4; ++r) { m[a][r] = -INFINITY; lsum[a][r] = 0.f; }

    const size_t kvbase = (size_t)(b * Hn + h);
    const short* kbh = kh_  + kvbase * Tn * 64;     // [t][64]
    const short* kbl = kl_  + kvbase * Tn * 64;
    const short* vbh = vth_ + kvbase * 64 * Tn;     // [d][2048]
    const short* vbl = vtl_ + kvbase * 64 * Tn;

    const int qwave  = 128 * qb + 32 * w;           // wave's first q row
    const int ntiles = (qwave + 31) / 64 + 1;       // wave-private tile count

    for (int kt = 0; kt < ntiles; ++kt) {
        // ---- QK^T: S[32q x 64k], B-frags direct from global K [k][d] ----
        f32x4 sa[2][4];
        #pragma unroll
        for (int a = 0; a < 2; ++a)
            #pragma unroll
            for (int t = 0; t < 4; ++t) sa[a][t] = (f32x4){0.f, 0.f, 0.f, 0.f};
        #pragma unroll
        for (int t = 0; t < 4; ++t) {
            const size_t krow = (size_t)(64 * kt + 16 * t + c16) * 64;
            const bf16x8 kh0 = *(const bf16x8*)(kbh + krow + 8 * g);
            const bf16x8 kh1 = *(const bf16x8*)(kbh + krow + 32 + 8 * g);
            const bf16x8 kl0 = *(const bf16x8*)(kbl + krow + 8 * g);
            const bf16x8 kl1 = *(const bf16x8*)(kbl + krow + 32 + 8 * g);
            #pragma unroll
            for (int a = 0; a < 2; ++a) {
                sa[a][t] = __builtin_amdgcn_mfma_f32_16x16x32_bf16(qh[a][0], kh0, sa[a][t], 0, 0, 0);
                sa[a][t] = __builtin_amdgcn_mfma_f32_16x16x32_bf16(qh[a][1], kh1, sa[a][t], 0, 0, 0);
                sa[a][t] = __builtin_amdgcn_mfma_f32_16x16x32_bf16(qh[a][0], kl0, sa[a][t], 0, 0, 0);
                sa[a][t] = __builtin_amdgcn_mfma_f32_16x16x32_bf16(qh[a][1], kl1, sa[a][t], 0, 0, 0);
                sa[a][t] = __builtin_amdgcn_mfma_f32_16x16x32_bf16(ql[a][0], kh0, sa[a][t], 0, 0, 0);
                sa[a][t] = __builtin_amdgcn_mfma_f32_16x16x32_bf16(ql[a][1], kh1, sa[a][t], 0, 0, 0);
            }
        }

        // ---- scale + causal mask (acc layout: col k=16t+c16, row q=4g+r) ----
        #pragma unroll
        for (int a = 0; a < 2; ++a)
            #pragma unroll
            for (int t = 0; t < 4; ++t)
                #pragma unroll
                for (int r = 0; r < 4; ++r) {
                    float v = sa[a][t][r] * 0.125f;
                    if (64 * kt + 16 * t + c16 > qwave + 16 * a + 4 * g + r)
                        v = -INFINITY;
                    sa[a][t][r] = v;
                }
        // ---- online softmax (row-reduce in 16-lane c16 group) ----
        #pragma unroll
        for (int a = 0; a < 2; ++a)
            #pragma unroll
            for (int r = 0; r < 4; ++r) {
                float mt = fmaxf(fmaxf(sa[a][0][r], sa[a][1][r]),
                                 fmaxf(sa[a][2][r], sa[a][3][r]));
                mt = fmaxf(mt, __shfl_xor(mt, 1));
                mt = fmaxf(mt, __shfl_xor(mt, 2));
                mt = fmaxf(mt, __shfl_xor(mt, 4));
                mt = fmaxf(mt, __shfl_xor(mt, 8));
                const float mnew = fmaxf(m[a][r], mt);     // always finite
                const float corr = __expf(m[a][r] - mnew);
                m[a][r] = mnew;
                float rs = 0.f;
                #pragma unroll
                for (int t = 0; t < 4; ++t) {
                    const float pe = __expf(sa[a][t][r] - mnew);
                    sa[a][t][r] = pe;
                    rs += pe;
                }
                rs += __shfl_xor(rs, 1);
                rs += __shfl_xor(rs, 2);
                rs += __shfl_xor(rs, 4);
                rs += __shfl_xor(rs, 8);
                lsum[a][r] = lsum[a][r] * corr + rs;
                #pragma unroll
                for (int j = 0; j < 4; ++j) Y[a][j][r] *= corr;
            }

        // ---- P -> wave-private LDS (hi/lo) ----
        #pragma unroll
        for (int a = 0; a < 2; ++a)
            #pragma unroll
            for (int t = 0; t < 4; ++t)
                #pragma unroll
                for (int r = 0; r < 4; ++r) {
                    const float pv = sa[a][t][r];
                    const unsigned short ph = f32_bf16(pv);
                    Ph[32 * w + 16 * a + 4 * g + r][16 * t + c16] = (short)ph;
                    Pl[32 * w + 16 * a + 4 * g + r][16 * t + c16] =
                        (short)f32_bf16(pv - bf16_f32(ph));
                }
        bf16x8 pfh[2][2], pfl[2][2];
        #pragma unroll
        for (int a = 0; a < 2; ++a) {
            const int row = 32 * w + 16 * a + c16;
            pfh[a][0] = *(const bf16x8*)&Ph[row][8 * g];
            pfh[a][1] = *(const bf16x8*)&Ph[row][32 + 8 * g];
            pfl[a][0] = *(const bf16x8*)&Pl[row][8 * g];
            pfl[a][1] = *(const bf16x8*)&Pl[row][32 + 8 * g];
        }

        // ---- PV: Y += P @ V, B-frags direct from global Vt [d][t] ----
        #pragma unroll
        for (int j = 0; j < 4; ++j) {
            const size_t vrow = (size_t)(16 * j + c16) * Tn + 64 * kt;
            #pragma unroll
            for (int kc = 0; kc < 2; ++kc) {
                const bf16x8 vh = *(const bf16x8*)(vbh + vrow + 32 * kc + 8 * g);
                const bf16x8 vl = *(const bf16x8*)(vbl + vrow + 32 * kc + 8 * g);
                #pragma unroll
                for (int a = 0; a < 2; ++a) {
                    Y[a][j] = __builtin_amdgcn_mfma_f32_16x16x32_bf16(pfh[a][kc], vh, Y[a][j], 0, 0, 0);
                    Y[a][j] = __builtin_amdgcn_mfma_f32_16x16x32_bf16(pfh[a][kc], vl, Y[a][j], 0, 0, 0);
                    Y[a][j] = __builtin_amdgcn_mfma_f32_16x16x32_bf16(pfl[a][kc], vh, Y[a][j], 0, 0, 0);
                }
            }
        }
    }

    // ---- epilogue: normalize, store ----
    #pragma unroll
    for (int a = 0; a < 2; ++a)
        #pragma unroll
        for (int r = 0; r < 4; ++r) {
            const float inv = 1.f / lsum[a][r];
            const int row = qwave + 16 * a + 4 * g + r;
            #pragma unroll
            for (int j = 0; j < 4; ++j)
                y[(size_t)(b * Tn + row) * Cn + h * Dn + 16 * j + c16] = Y[a][j][r] * inv;
        }
}

// ---------------------------------------------------------------------------
extern "C" void kernel_launch(void* const* d_in, const int* in_sizes, int n_in,
                              void* d_out, int out_size, void* d_ws, size_t ws_size,
                              hipStream_t stream) {
    const float* x    = (const float*)d_in[0];  // [B,T,C]
    const float* Wqkv = (const float*)d_in[1];  // [C,3C]
    const float* bqkv = (const float*)d_in[2];  // [3C]
    const float* Wo   = (const float*)d_in[3];  // [C,C]
    const float* bo   = (const float*)d_in[4];  // [C]
    float* out = (float*)d_out;                 // [B,T,C] fp32

    const int M = Bn * Tn;                      // 4096
    // ws layout (64 MB total):
    float* qbuf = (float*)d_ws;                 // [4096,1024] fp32   16 MB
    float* yat  = qbuf + (size_t)M * Cn;        // [4096,1024] fp32   16 MB
    short* kh   = (short*)(yat + (size_t)M * Cn);           // 8 MB
    short* kl   = kh  + (size_t)Bn * Hn * Tn * 64;          // 8 MB
    short* vth  = kl  + (size_t)Bn * Hn * Tn * 64;          // 8 MB
    short* vtl  = vth + (size_t)Bn * Hn * Tn * 64;          // 8 MB

    // 1) qkv GEMM: Q -> fp32 qbuf; K,V -> hi/lo bf16 (V transposed)
    {
        dim3 grid(3072 / 128, M / 128), blk(256);
        gemm_qkv<<<grid, blk, 0, stream>>>(x, Wqkv, bqkv, qbuf, kh, kl, vth, vtl);
    }
    // 2) causal MFMA flash attention: 512 blocks (b,h,128-row q-tile)
    {
        dim3 grid(512), blk(256);
        attn_mfma2<<<grid, blk, 0, stream>>>(qbuf, kh, kl, vth, vtl, yat);
    }
    // 3) out = yat @ Wo + bo
    {
        dim3 grid(Cn / 128, M / 128), blk(256);
        gemm_mfma3<<<grid, blk, 0, stream>>>(yat, Wo, bo, out, M, Cn, Cn);
    }
}